// Round 12
// baseline (725.848 us; speedup 1.0000x reference)
//
#include <hip/hip_runtime.h>
#include <hip/hip_bf16.h>

typedef __bf16 bf16_t;
typedef __bf16 bf16x4 __attribute__((ext_vector_type(4)));
typedef __bf16 bf16x8 __attribute__((ext_vector_type(8)));
typedef float f32x4 __attribute__((ext_vector_type(4)));

#define E_DIM 1024
#define SEQ   2048
#define NBATCH 4

#define BARR()  asm volatile("s_barrier" ::: "memory")
#define LGKM0() asm volatile("s_waitcnt lgkmcnt(0)" ::: "memory")
#define VMC6()  asm volatile("s_waitcnt vmcnt(6)" ::: "memory")
#define VMC0()  asm volatile("s_waitcnt vmcnt(0)" ::: "memory")

// ---------------- all casts in one dispatch (plain row-major bf16) -------------
__global__ __launch_bounds__(256) void k_cast_all(
    const float* __restrict__ q, const float* __restrict__ k, const float* __restrict__ v,
    const float* __restrict__ wq, const float* __restrict__ wk,
    const float* __restrict__ wv, const float* __restrict__ wo,
    bf16_t* __restrict__ xq, bf16_t* __restrict__ xk, bf16_t* __restrict__ xv,
    bf16_t* __restrict__ wqb, bf16_t* __restrict__ wkb,
    bf16_t* __restrict__ wvb, bf16_t* __restrict__ wob) {
  const int b = blockIdx.x;
  const float* s; bf16_t* d; long base;
  if (b < 4096)        { s = q; d = xq; base = (long)b * 2048; }
  else if (b < 8192)   { s = k; d = xk; base = (long)(b - 4096) * 2048; }
  else if (b < 12288)  { s = v; d = xv; base = (long)(b - 8192) * 2048; }
  else {
    const int w = (b - 12288) >> 9, r = (b - 12288) & 511;
    s = (w == 0) ? wq : (w == 1) ? wk : (w == 2) ? wv : wo;
    d = (w == 0) ? wqb : (w == 1) ? wkb : (w == 2) ? wvb : wob;
    base = (long)r * 2048;
  }
  const long i = base + threadIdx.x * 8;
  const float4 a = *(const float4*)(s + i);
  const float4 c = *(const float4*)(s + i + 4);
  bf16x8 o;
  o[0] = (bf16_t)a.x; o[1] = (bf16_t)a.y; o[2] = (bf16_t)a.z; o[3] = (bf16_t)a.w;
  o[4] = (bf16_t)c.x; o[5] = (bf16_t)c.y; o[6] = (bf16_t)c.z; o[7] = (bf16_t)c.w;
  *(bf16x8*)(d + i) = o;
}

// =================================================================================
// PERSISTENT 4-phase GEMM, round-10 core verbatim.  Rule-#20-safe persistence:
// per-rep staging/epilogue bases are NAMED scalars selected by ternaries (never
// runtime-indexed arrays -> no scratch demotion; verify via VGPR_Count ~80-100).
// Tile 128x128, BK=64, 4 waves (2x2), per-wave 64x64, mfma_f32_16x16x32_bf16,
// conflict-free XOR-8 LDS swizzle, 2x32KB LDS (2 wg/CU), counted vmcnt ledger:
// 8 GLL/tile; end-of-tile VMC6 retires tile t+1's 8, keeps t+2's 6 in flight.
// Reps share one continuous pipeline; mid-loop epilogue stores from registers.
// OUTMODE 0:f32+bias+residual, 1:bf16+bias, 3:bf16 exp(v*scale).
// RS: ones-MFMA rowsum (lane-local), rows scaled by 1/rs (PV normalize).
// QKV3: REPS=3 slabs (Q,K,V) at same (bm,bn); slab 2 stores transposed Vt.
// =================================================================================
template <int OUTMODE, bool RS, bool QKV3, int REPS, int NTL>
__global__ __launch_bounds__(256, 2) void k_g12(
    const bf16_t* __restrict__ A, int lda, long sA,
    const bf16_t* __restrict__ B, int ldb, long sB,
    void* __restrict__ Cv, int ldc, long sC,
    float scale, const float* __restrict__ bias,
    const float* __restrict__ residual, int GM, int GN,
    const bf16_t* __restrict__ A1, const bf16_t* __restrict__ A2,
    const bf16_t* __restrict__ B1, const bf16_t* __restrict__ B2,
    const float* __restrict__ bias1, const float* __restrict__ bias2,
    void* __restrict__ Cv1, void* __restrict__ Cv2) {
  constexpr int ASZ   = 16384;           // A tile bytes (128 x 64 bf16)
  constexpr int BUFSZ = 32768;           // A + B per buffer
  constexpr int NT    = 1 << NTL;        // K-tiles per output tile
  constexpr int TT    = REPS << NTL;     // total K-tiles per wg
  extern __shared__ char smem[];

  const int tid  = threadIdx.x;
  const int lane = tid & 63;
  const int wid  = tid >> 6;
  const int wm   = wid >> 1;             // 0..1
  const int wn   = wid & 1;              // 0..1
  const int l15  = lane & 15;
  const int lq   = lane >> 4;            // k-chunk 0..3

  // T1: XCD swizzle (grids are multiples of 8)
  const int nwg  = gridDim.x;
  const int orig = blockIdx.x;
  const int wg   = (orig & 7) * (nwg >> 3) + (orig >> 3);

  // staging source invariants (inverse-swizzled col; rule 21)
  const int colk = ((tid & 7) ^ ((tid >> 3) & 7)) << 3;
  const int trow = tid >> 3;
  const int ldsw = wid << 10;            // 4 waves x 1KB = one 4KB (32-row) unit

  // -------- per-rep NAMED bases (no arrays; ternary selection only) -----------
  const bf16_t *pA0, *pB0, *pA1 = nullptr, *pB1 = nullptr, *pA2 = nullptr, *pB2 = nullptr;
  int zzr0 = 0, bmr0 = 0, bnr0 = 0, zzr1 = 0, bmr1 = 0, bnr1 = 0;
  if constexpr (QKV3) {
    bmr0 = wg / GN; bnr0 = wg - bmr0 * GN;
    const long aoff = (long)(bmr0 * 128 + trow) * lda + colk;
    const long boff = (long)(bnr0 * 128 + trow) * ldb + colk;
    pA0 = A + aoff;  pA1 = A1 + aoff;  pA2 = A2 + aoff;
    pB0 = B + boff;  pB1 = B1 + boff;  pB2 = B2 + boff;
  } else {
    {
      const int g  = wg;
      zzr0 = g / (GM * GN);
      const int rm = g - zzr0 * (GM * GN);
      bmr0 = rm / GN; bnr0 = rm - bmr0 * GN;
      pA0 = A + zzr0 * sA + (long)(bmr0 * 128 + trow) * lda + colk;
      pB0 = B + zzr0 * sB + (long)(bnr0 * 128 + trow) * ldb + colk;
    }
    if constexpr (REPS >= 2) {
      const int g  = nwg + wg;
      zzr1 = g / (GM * GN);
      const int rm = g - zzr1 * (GM * GN);
      bmr1 = rm / GN; bnr1 = rm - bmr1 * GN;
      pA1 = A + zzr1 * sA + (long)(bmr1 * 128 + trow) * lda + colk;
      pB1 = B + zzr1 * sB + (long)(bnr1 * 128 + trow) * ldb + colk;
    }
  }

#define GLL(gaddr, ldsoff)                                                       \
  __builtin_amdgcn_global_load_lds(                                             \
      (const __attribute__((address_space(1))) void*)(gaddr),                   \
      (__attribute__((address_space(3))) void*)(smem + (ldsoff)), 16, 0, 0)

  auto stA = [&](int tau, int buf) {           // full A tile: 4 x 4KB units
    tau = tau < TT ? tau : TT - 1;
    const int rep = tau >> NTL;
    const bf16_t* p = (REPS == 1) ? pA0
                    : (REPS == 2) ? (rep ? pA1 : pA0)
                    : (rep == 0 ? pA0 : (rep == 1 ? pA1 : pA2));
    p += (long)(tau & (NT - 1)) * 64;
#pragma unroll
    for (int s = 0; s < 4; ++s)
      GLL(p + (long)(s * 32) * lda, buf * BUFSZ + s * 4096 + ldsw);
  };
  auto stB = [&](int tau, int buf, int half) { // B half: 2 x 4KB units
    tau = tau < TT ? tau : TT - 1;
    const int rep = tau >> NTL;
    const bf16_t* p = (REPS == 1) ? pB0
                    : (REPS == 2) ? (rep ? pB1 : pB0)
                    : (rep == 0 ? pB0 : (rep == 1 ? pB1 : pB2));
    p += (long)(tau & (NT - 1)) * 64;
#pragma unroll
    for (int s = 0; s < 2; ++s)
      GLL(p + (long)(half * 64 + s * 32) * ldb,
          buf * BUFSZ + ASZ + half * 8192 + s * 4096 + ldsw);
  };

  f32x4 acc[4][4];
#pragma unroll
  for (int m = 0; m < 4; ++m)
#pragma unroll
    for (int n = 0; n < 4; ++n) acc[m][n] = (f32x4){0.f, 0.f, 0.f, 0.f};
  f32x4 rs[4];
#pragma unroll
  for (int m = 0; m < 4; ++m) rs[m] = (f32x4){0.f, 0.f, 0.f, 0.f};
  bf16x8 vones;
#pragma unroll
  for (int i = 0; i < 8; ++i) vones[i] = (bf16_t)1.0f;

  // ds_read fragment loaders (swizzled, conflict-free)
  auto ldA = [&](bf16x8 (&a)[2][2], int cur, int mq) {
#pragma unroll
    for (int i = 0; i < 2; ++i) {
      const int row = wm * 64 + (mq * 2 + i) * 16 + l15;
#pragma unroll
      for (int kk = 0; kk < 2; ++kk) {
        const int byt = cur * BUFSZ + row * 128 + ((kk * 64 + lq * 16) ^ ((row & 7) << 4));
        a[i][kk] = *(const bf16x8*)(smem + byt);
      }
    }
  };
  auto ldB = [&](bf16x8 (&b)[2][2], int cur, int nq) {
#pragma unroll
    for (int n2 = 0; n2 < 2; ++n2) {
      const int row = wn * 64 + (nq * 2 + n2) * 16 + l15;
#pragma unroll
      for (int kk = 0; kk < 2; ++kk) {
        const int byt = cur * BUFSZ + ASZ + row * 128 + ((kk * 64 + lq * 16) ^ ((row & 7) << 4));
        b[n2][kk] = *(const bf16x8*)(smem + byt);
      }
    }
  };
  auto mmaq = [&](bf16x8 (&a)[2][2], bf16x8 (&b)[2][2], int mq, int nq) {
    __builtin_amdgcn_s_setprio(1);
#pragma unroll
    for (int kk = 0; kk < 2; ++kk)
#pragma unroll
      for (int i = 0; i < 2; ++i)
#pragma unroll
        for (int n2 = 0; n2 < 2; ++n2)
          acc[mq * 2 + i][nq * 2 + n2] = __builtin_amdgcn_mfma_f32_16x16x32_bf16(
              a[i][kk], b[n2][kk], acc[mq * 2 + i][nq * 2 + n2], 0, 0, 0);
    __builtin_amdgcn_s_setprio(0);
  };
  auto mmars = [&](bf16x8 (&a)[2][2], int mq) {
#pragma unroll
    for (int kk = 0; kk < 2; ++kk)
#pragma unroll
      for (int i = 0; i < 2; ++i)
        rs[mq * 2 + i] = __builtin_amdgcn_mfma_f32_16x16x32_bf16(
            a[i][kk], vones, rs[mq * 2 + i], 0, 0, 0);
  };

  // mid-loop epilogue: store rep's output from registers, reset accumulators.
  auto epi = [&](int rep) {
    int zz2, bm2, bn2;
    const float* biasp;
    void* Cvp;
    bool tr = false;
    if constexpr (QKV3) {
      zz2 = 0; bm2 = bmr0; bn2 = bnr0;
      biasp = rep == 0 ? bias : (rep == 1 ? bias1 : bias2);
      Cvp   = rep == 0 ? Cv   : (rep == 1 ? Cv1   : Cv2);
      tr = (rep == 2);
    } else {
      zz2 = (REPS >= 2 && rep) ? zzr1 : zzr0;
      bm2 = (REPS >= 2 && rep) ? bmr1 : bmr0;
      bn2 = (REPS >= 2 && rep) ? bnr1 : bnr0;
      biasp = bias; Cvp = Cv;
    }
    const int colb = bn2 * 128 + wn * 64 + l15;
    const int rowb = bm2 * 128 + wm * 64 + lq * 4;
#pragma unroll
    for (int m = 0; m < 4; ++m) {
      float inv[4];
      if constexpr (RS) {
#pragma unroll
        for (int j = 0; j < 4; ++j) inv[j] = 1.0f / rs[m][j];
      }
#pragma unroll
      for (int n = 0; n < 4; ++n) {
        const int colg = colb + n * 16;
        float bval = 0.0f;
        if constexpr (OUTMODE != 3) bval = biasp ? biasp[colg] : 0.0f;
        if (QKV3 && tr) {
          const int r0 = rowb + m * 16;
          bf16x4 pk;
#pragma unroll
          for (int j = 0; j < 4; ++j) pk[j] = (bf16_t)(acc[m][n][j] * scale + bval);
          const long bb = (long)(r0 >> 11);
          const int ss = r0 & (SEQ - 1);
          *(bf16x4*)((bf16_t*)Cvp + bb * ((long)E_DIM * SEQ) + (long)colg * SEQ + ss) = pk;
        } else {
#pragma unroll
          for (int j = 0; j < 4; ++j) {
            const int r = rowb + m * 16 + j;
            float v;
            if constexpr (OUTMODE == 3) v = __expf(acc[m][n][j] * scale);
            else v = acc[m][n][j] * scale + bval;
            if constexpr (RS) v *= inv[j];
            if (OUTMODE == 0 && residual) v += residual[(long)r * ldc + colg];
            const long idx = (long)zz2 * sC + (long)r * ldc + colg;
            if constexpr (OUTMODE == 0) ((float*)Cvp)[idx] = v;
            else ((bf16_t*)Cvp)[idx] = (bf16_t)v;
          }
        }
      }
    }
#pragma unroll
    for (int m = 0; m < 4; ++m) {
#pragma unroll
      for (int n = 0; n < 4; ++n) acc[m][n] = (f32x4){0.f, 0.f, 0.f, 0.f};
      rs[m] = (f32x4){0.f, 0.f, 0.f, 0.f};
    }
  };

  // ---------------- prologue: t0 full (8) + t1 {Bh0 (2), A (4)}; VMC6 -----------
  stB(0, 0, 0); stB(0, 0, 1); stA(0, 0);
  stB(1, 1, 0); stA(1, 1);
  VMC6();   // 14 outstanding -> retire tile0's 8, keep t1's 6
  BARR();

  bf16x8 a0[2][2], a1[2][2], b0[2][2], b1[2][2];
  auto tile = [&](int t, int cur) {
    // ph0: reads a0,b0 ; stage Bh1(t+1)->buf^1
    ldA(a0, cur, 0); ldB(b0, cur, 0);
    stB(t + 1, cur ^ 1, 1);
    BARR(); LGKM0();
    mmaq(a0, b0, 0, 0);
    BARR();
    // ph1: reads b1
    ldB(b1, cur, 1);
    BARR(); LGKM0();
    mmaq(a0, b1, 0, 1);
    if constexpr (RS) mmars(a0, 0);
    BARR();
    // ph2: reads a1 ; stage Bh0(t+2)->cur
    ldA(a1, cur, 1);
    stB(t + 2, cur, 0);
    BARR(); LGKM0();
    mmaq(a1, b1, 1, 1);
    BARR();
    // ph3: stage A(t+2)->cur; counted vmcnt (never drains)
    stA(t + 2, cur);
    BARR();
    mmaq(a1, b0, 1, 0);
    if constexpr (RS) mmars(a1, 1);
    VMC6();   // retire tile t+1's 8 loads; keep tile t+2's 6 in flight
    BARR();
    // rep boundary: store output from regs, keep pipeline hot
    if (((t + 1) & (NT - 1)) == 0) epi(t >> NTL);
  };

  for (int t = 0; t < TT; t += 2) {
    tile(t, 0);
    tile(t + 1, 1);
  }
  VMC0();
#undef GLL
}

// ---------------- layernorm in-place on rows of 1024 f32 ----------------
__global__ __launch_bounds__(256) void k_layernorm(float* __restrict__ out,
                                                   const float* __restrict__ gamma,
                                                   const float* __restrict__ beta) {
  const long row = blockIdx.x;
  float* rp = out + row * 1024;
  const int t = threadIdx.x;
  const float4 v = *(const float4*)(rp + t * 4);
  float s = v.x + v.y + v.z + v.w;
#pragma unroll
  for (int o = 32; o; o >>= 1) s += __shfl_xor(s, o);
  __shared__ float red1[4], red2[4];
  const int lane = t & 63, w = t >> 6;
  if (lane == 0) red1[w] = s;
  __syncthreads();
  const float mu = (red1[0] + red1[1] + red1[2] + red1[3]) * (1.0f / 1024.0f);
  const float d0 = v.x - mu, d1 = v.y - mu, d2 = v.z - mu, d3 = v.w - mu;
  float ss = d0 * d0 + d1 * d1 + d2 * d2 + d3 * d3;
#pragma unroll
  for (int o = 32; o; o >>= 1) ss += __shfl_xor(ss, o);
  if (lane == 0) red2[w] = ss;
  __syncthreads();
  const float var = (red2[0] + red2[1] + red2[2] + red2[3]) * (1.0f / 1024.0f);
  const float rsq = rsqrtf(var + 1e-6f);
  const float4 g = *(const float4*)(gamma + t * 4);
  const float4 b = *(const float4*)(beta + t * 4);
  float4 o;
  o.x = d0 * rsq * g.x + b.x;
  o.y = d1 * rsq * g.y + b.y;
  o.z = d2 * rsq * g.z + b.z;
  o.w = d3 * rsq * g.w + b.w;
  *(float4*)(rp + t * 4) = o;
}

extern "C" void kernel_launch(void* const* d_in, const int* in_sizes, int n_in,
                              void* d_out, int out_size, void* d_ws, size_t ws_size,
                              hipStream_t stream) {
  const float* query = (const float*)d_in[0];
  const float* key   = (const float*)d_in[1];
  const float* value = (const float*)d_in[2];
  const float* Wq = (const float*)d_in[3];
  const float* bq = (const float*)d_in[4];
  const float* Wk = (const float*)d_in[5];
  const float* bk = (const float*)d_in[6];
  const float* Wv = (const float*)d_in[7];
  const float* bv = (const float*)d_in[8];
  const float* Wo = (const float*)d_in[9];
  const float* bo = (const float*)d_in[10];
  const float* gamma = (const float*)d_in[11];
  const float* beta  = (const float*)d_in[12];
  float* out = (float*)d_out;

  char* ws = (char*)d_ws;
  const size_t XSZ = (size_t)NBATCH * SEQ * E_DIM * 2;  // 16 MiB
  const size_t WSZ = (size_t)E_DIM * E_DIM * 2;         // 2 MiB
  const size_t B2  = 3 * XSZ;                           // 48 MiB boundary

  bf16_t* Xq  = (bf16_t*)(ws + 0);
  bf16_t* Xk  = (bf16_t*)(ws + XSZ);
  bf16_t* Xv  = (bf16_t*)(ws + 2 * XSZ);
  bf16_t* SC  = (bf16_t*)(ws + 0);   // exp-scores overlay dead X buffers (33.5MB<48)
  bf16_t* Wqb = (bf16_t*)(ws + B2);
  bf16_t* Wkb = (bf16_t*)(ws + B2 + WSZ);
  bf16_t* Wvb = (bf16_t*)(ws + B2 + 2 * WSZ);
  bf16_t* Wob = (bf16_t*)(ws + B2 + 3 * WSZ);
  bf16_t* Qb  = (bf16_t*)(ws + B2 + 4 * WSZ);
  bf16_t* Kb  = (bf16_t*)(ws + B2 + 4 * WSZ + XSZ);
  bf16_t* Vt  = (bf16_t*)(ws + B2 + 4 * WSZ + 2 * XSZ);
  bf16_t* Ctx = (bf16_t*)(ws + B2 + 4 * WSZ + 3 * XSZ);

  const int NTOK = NBATCH * SEQ;  // 8192
  const int SMB = 65536;          // 2 x 32KB -> 2 wg/CU

  hipFuncSetAttribute((const void*)k_g12<1, false, true, 3, 4>, hipFuncAttributeMaxDynamicSharedMemorySize, SMB);
  hipFuncSetAttribute((const void*)k_g12<3, false, false, 2, 4>, hipFuncAttributeMaxDynamicSharedMemorySize, SMB);
  hipFuncSetAttribute((const void*)k_g12<1, true, false, 1, 5>, hipFuncAttributeMaxDynamicSharedMemorySize, SMB);
  hipFuncSetAttribute((const void*)k_g12<0, false, false, 1, 4>, hipFuncAttributeMaxDynamicSharedMemorySize, SMB);

  // 1) casts
  k_cast_all<<<dim3(14336), 256, 0, stream>>>(query, key, value, Wq, Wk, Wv, Wo,
                                              Xq, Xk, Xv, Wqb, Wkb, Wvb, Wob);

  // 2) persistent merged Q/K/V projections: grid 512, REPS=3 slabs per wg
  k_g12<1, false, true, 3, 4><<<512, 256, SMB, stream>>>(
      Xq, E_DIM, 0, Wqb, E_DIM, 0, Qb, E_DIM, 0, 1.0f, bq, nullptr, 64, 8,
      Xk, Xv, Wkb, Wvb, bk, bv, Kb, Vt);

  // 3) P = exp(Q K^T / 32): grid 512, REPS=2 (16x16x4 = 1024 tiles)
  k_g12<3, false, false, 2, 4><<<512, 256, SMB, stream>>>(
      Qb, E_DIM, (long)SEQ * E_DIM, Kb, E_DIM, (long)SEQ * E_DIM,
      SC, SEQ, (long)SEQ * SEQ, 0.03125f, nullptr, nullptr, 16, 16,
      nullptr, nullptr, nullptr, nullptr, nullptr, nullptr, nullptr, nullptr);

  // 4) ctx = (P @ V) / rowsum: grid 512, REPS=1, NT=32
  k_g12<1, true, false, 1, 5><<<512, 256, SMB, stream>>>(
      SC, SEQ, (long)SEQ * SEQ, Vt, SEQ, (long)E_DIM * SEQ,
      Ctx, E_DIM, (long)SEQ * E_DIM, 1.0f, nullptr, nullptr, 16, 8,
      nullptr, nullptr, nullptr, nullptr, nullptr, nullptr, nullptr, nullptr);

  // 5) out = ctx Wo^T + bo + residual(query): grid 512, REPS=1
  k_g12<0, false, false, 1, 4><<<512, 256, SMB, stream>>>(
      Ctx, E_DIM, 0, Wob, E_DIM, 0, out, E_DIM, 0, 1.0f, bo, query, 64, 8,
      nullptr, nullptr, nullptr, nullptr, nullptr, nullptr, nullptr, nullptr);

  // 6) layernorm in-place
  k_layernorm<<<dim3(NTOK), 256, 0, stream>>>(out, gamma, beta);
}

// Round 13
// 225.161 us; speedup vs baseline: 3.2237x; 3.2237x over previous
//
#include <hip/hip_runtime.h>
#include <hip/hip_bf16.h>

typedef __bf16 bf16_t;
typedef __bf16 bf16x4 __attribute__((ext_vector_type(4)));
typedef __bf16 bf16x8 __attribute__((ext_vector_type(8)));
typedef float f32x4 __attribute__((ext_vector_type(4)));

#define E_DIM 1024
#define SEQ   2048
#define NBATCH 4

#define BARR()  asm volatile("s_barrier" ::: "memory")
#define LGKM0() asm volatile("s_waitcnt lgkmcnt(0)" ::: "memory")
#define VMC6()  asm volatile("s_waitcnt vmcnt(6)" ::: "memory")
#define VMC0()  asm volatile("s_waitcnt vmcnt(0)" ::: "memory")

// ---------------- all casts in one dispatch (plain row-major bf16) -------------
__global__ __launch_bounds__(256) void k_cast_all(
    const float* __restrict__ q, const float* __restrict__ k, const float* __restrict__ v,
    const float* __restrict__ wq, const float* __restrict__ wk,
    const float* __restrict__ wv, const float* __restrict__ wo,
    bf16_t* __restrict__ xq, bf16_t* __restrict__ xk, bf16_t* __restrict__ xv,
    bf16_t* __restrict__ wqb, bf16_t* __restrict__ wkb,
    bf16_t* __restrict__ wvb, bf16_t* __restrict__ wob) {
  const int b = blockIdx.x;
  const float* s; bf16_t* d; long base;
  if (b < 4096)        { s = q; d = xq; base = (long)b * 2048; }
  else if (b < 8192)   { s = k; d = xk; base = (long)(b - 4096) * 2048; }
  else if (b < 12288)  { s = v; d = xv; base = (long)(b - 8192) * 2048; }
  else {
    const int w = (b - 12288) >> 9, r = (b - 12288) & 511;
    s = (w == 0) ? wq : (w == 1) ? wk : (w == 2) ? wv : wo;
    d = (w == 0) ? wqb : (w == 1) ? wkb : (w == 2) ? wvb : wob;
    base = (long)r * 2048;
  }
  const long i = base + threadIdx.x * 8;
  const float4 a = *(const float4*)(s + i);
  const float4 c = *(const float4*)(s + i + 4);
  bf16x8 o;
  o[0] = (bf16_t)a.x; o[1] = (bf16_t)a.y; o[2] = (bf16_t)a.z; o[3] = (bf16_t)a.w;
  o[4] = (bf16_t)c.x; o[5] = (bf16_t)c.y; o[6] = (bf16_t)c.z; o[7] = (bf16_t)c.w;
  *(bf16x8*)(d + i) = o;
}

// =================================================================================
// PERSISTENT 4-phase GEMM v3 (inlining-safe).  Round-10 core verbatim; the rep
// loop is top-level `#pragma unroll` (rep compile-time per copy) and the per-rep
// epilogue is STRAIGHT INLINE CODE in the loop body -- no lambda call around the
// accumulator (r11/r12 failure: tile+epi lambda exceeded inline threshold ->
// by-ref acc demoted to scratch: VGPR 52, 1.8GB scratch writes).
// Tile 128x128, BK=64, 4 waves (2x2), per-wave 64x64, mfma_f32_16x16x32_bf16,
// conflict-free XOR-8 LDS swizzle, 2x32KB LDS (2 wg/CU), counted vmcnt ledger:
// 8 GLL/tile; end-of-tile VMC6 retires tile t+1's 8, keeps t+2's 6 in flight.
// Reps share one continuous pipeline (staging indexed by global tau; at rep
// boundary the in-flight prefetch already targets the next rep's panels).
// OUTMODE 0:f32+bias+residual, 1:bf16+bias, 3:bf16 exp(v*scale).
// RS: ones-MFMA rowsum (lane-local), rows scaled by 1/rs (PV normalize).
// QKV3: REPS=3 slabs (Q,K,V) at same (bm,bn); slab 2 stores transposed Vt.
// =================================================================================
template <int OUTMODE, bool RS, bool QKV3, int REPS, int NTL>
__global__ __launch_bounds__(256, 2) void k_g13(
    const bf16_t* __restrict__ A, int lda, long sA,
    const bf16_t* __restrict__ B, int ldb, long sB,
    void* __restrict__ Cv, int ldc, long sC,
    float scale, const float* __restrict__ bias,
    const float* __restrict__ residual, int GM, int GN,
    const bf16_t* __restrict__ A1, const bf16_t* __restrict__ A2,
    const bf16_t* __restrict__ B1, const bf16_t* __restrict__ B2,
    const float* __restrict__ bias1, const float* __restrict__ bias2,
    void* __restrict__ Cv1, void* __restrict__ Cv2) {
  constexpr int ASZ   = 16384;           // A tile bytes (128 x 64 bf16)
  constexpr int BUFSZ = 32768;           // A + B per buffer
  constexpr int NT    = 1 << NTL;        // K-tiles per output tile
  constexpr int TT    = REPS << NTL;     // total K-tiles per wg
  extern __shared__ char smem[];

  const int tid  = threadIdx.x;
  const int lane = tid & 63;
  const int wid  = tid >> 6;
  const int wm   = wid >> 1;             // 0..1
  const int wn   = wid & 1;              // 0..1
  const int l15  = lane & 15;
  const int lq   = lane >> 4;            // k-chunk 0..3

  // T1: XCD swizzle (grids are multiples of 8)
  const int nwg  = gridDim.x;
  const int orig = blockIdx.x;
  const int wg   = (orig & 7) * (nwg >> 3) + (orig >> 3);

  // staging source invariants (inverse-swizzled col; rule 21)
  const int colk = ((tid & 7) ^ ((tid >> 3) & 7)) << 3;
  const int trow = tid >> 3;
  const int ldsw = wid << 10;            // 4 waves x 1KB = one 4KB (32-row) unit

  // -------- per-rep NAMED bases (ternary selection only; rule-#20-safe) -------
  const bf16_t *pA0, *pB0, *pA1 = nullptr, *pB1 = nullptr, *pA2 = nullptr, *pB2 = nullptr;
  int zzr0 = 0, bmr0 = 0, bnr0 = 0, zzr1 = 0, bmr1 = 0, bnr1 = 0;
  if constexpr (QKV3) {
    bmr0 = wg / GN; bnr0 = wg - bmr0 * GN;
    const long aoff = (long)(bmr0 * 128 + trow) * lda + colk;
    const long boff = (long)(bnr0 * 128 + trow) * ldb + colk;
    pA0 = A + aoff;  pA1 = A1 + aoff;  pA2 = A2 + aoff;
    pB0 = B + boff;  pB1 = B1 + boff;  pB2 = B2 + boff;
  } else {
    {
      const int g  = wg;
      zzr0 = g / (GM * GN);
      const int rm = g - zzr0 * (GM * GN);
      bmr0 = rm / GN; bnr0 = rm - bmr0 * GN;
      pA0 = A + zzr0 * sA + (long)(bmr0 * 128 + trow) * lda + colk;
      pB0 = B + zzr0 * sB + (long)(bnr0 * 128 + trow) * ldb + colk;
    }
    if constexpr (REPS >= 2) {
      const int g  = nwg + wg;
      zzr1 = g / (GM * GN);
      const int rm = g - zzr1 * (GM * GN);
      bmr1 = rm / GN; bnr1 = rm - bmr1 * GN;
      pA1 = A + zzr1 * sA + (long)(bmr1 * 128 + trow) * lda + colk;
      pB1 = B + zzr1 * sB + (long)(bnr1 * 128 + trow) * ldb + colk;
    }
  }

#define GLL(gaddr, ldsoff)                                                       \
  __builtin_amdgcn_global_load_lds(                                             \
      (const __attribute__((address_space(1))) void*)(gaddr),                   \
      (__attribute__((address_space(3))) void*)(smem + (ldsoff)), 16, 0, 0)

  auto stA = [&](int tau, int buf) {           // full A tile: 4 x 4KB units
    tau = tau < TT ? tau : TT - 1;
    const int rep = tau >> NTL;
    const bf16_t* p = (REPS == 1) ? pA0
                    : (REPS == 2) ? (rep ? pA1 : pA0)
                    : (rep == 0 ? pA0 : (rep == 1 ? pA1 : pA2));
    p += (long)(tau & (NT - 1)) * 64;
#pragma unroll
    for (int s = 0; s < 4; ++s)
      GLL(p + (long)(s * 32) * lda, buf * BUFSZ + s * 4096 + ldsw);
  };
  auto stB = [&](int tau, int buf, int half) { // B half: 2 x 4KB units
    tau = tau < TT ? tau : TT - 1;
    const int rep = tau >> NTL;
    const bf16_t* p = (REPS == 1) ? pB0
                    : (REPS == 2) ? (rep ? pB1 : pB0)
                    : (rep == 0 ? pB0 : (rep == 1 ? pB1 : pB2));
    p += (long)(tau & (NT - 1)) * 64;
#pragma unroll
    for (int s = 0; s < 2; ++s)
      GLL(p + (long)(half * 64 + s * 32) * ldb,
          buf * BUFSZ + ASZ + half * 8192 + s * 4096 + ldsw);
  };

  f32x4 acc[4][4];
#pragma unroll
  for (int m = 0; m < 4; ++m)
#pragma unroll
    for (int n = 0; n < 4; ++n) acc[m][n] = (f32x4){0.f, 0.f, 0.f, 0.f};
  f32x4 rs[4];
#pragma unroll
  for (int m = 0; m < 4; ++m) rs[m] = (f32x4){0.f, 0.f, 0.f, 0.f};
  bf16x8 vones;
#pragma unroll
  for (int i = 0; i < 8; ++i) vones[i] = (bf16_t)1.0f;

  // ds_read fragment loaders (swizzled, conflict-free)
  auto ldA = [&](bf16x8 (&a)[2][2], int cur, int mq) {
#pragma unroll
    for (int i = 0; i < 2; ++i) {
      const int row = wm * 64 + (mq * 2 + i) * 16 + l15;
#pragma unroll
      for (int kk = 0; kk < 2; ++kk) {
        const int byt = cur * BUFSZ + row * 128 + ((kk * 64 + lq * 16) ^ ((row & 7) << 4));
        a[i][kk] = *(const bf16x8*)(smem + byt);
      }
    }
  };
  auto ldB = [&](bf16x8 (&b)[2][2], int cur, int nq) {
#pragma unroll
    for (int n2 = 0; n2 < 2; ++n2) {
      const int row = wn * 64 + (nq * 2 + n2) * 16 + l15;
#pragma unroll
      for (int kk = 0; kk < 2; ++kk) {
        const int byt = cur * BUFSZ + ASZ + row * 128 + ((kk * 64 + lq * 16) ^ ((row & 7) << 4));
        b[n2][kk] = *(const bf16x8*)(smem + byt);
      }
    }
  };
  auto mmaq = [&](bf16x8 (&a)[2][2], bf16x8 (&b)[2][2], int mq, int nq) {
    __builtin_amdgcn_s_setprio(1);
#pragma unroll
    for (int kk = 0; kk < 2; ++kk)
#pragma unroll
      for (int i = 0; i < 2; ++i)
#pragma unroll
        for (int n2 = 0; n2 < 2; ++n2)
          acc[mq * 2 + i][nq * 2 + n2] = __builtin_amdgcn_mfma_f32_16x16x32_bf16(
              a[i][kk], b[n2][kk], acc[mq * 2 + i][nq * 2 + n2], 0, 0, 0);
    __builtin_amdgcn_s_setprio(0);
  };
  auto mmars = [&](bf16x8 (&a)[2][2], int mq) {
#pragma unroll
    for (int kk = 0; kk < 2; ++kk)
#pragma unroll
      for (int i = 0; i < 2; ++i)
        rs[mq * 2 + i] = __builtin_amdgcn_mfma_f32_16x16x32_bf16(
            a[i][kk], vones, rs[mq * 2 + i], 0, 0, 0);
  };

  // ---------------- prologue: t0 full (8) + t1 {Bh0 (2), A (4)}; VMC6 -----------
  stB(0, 0, 0); stB(0, 0, 1); stA(0, 0);
  stB(1, 1, 0); stA(1, 1);
  VMC6();   // 14 outstanding -> retire tile0's 8, keep t1's 6
  BARR();

  bf16x8 a0[2][2], a1[2][2], b0[2][2], b1[2][2];
  // lean tile lambda -- EXACT round-10 size (inlines; acc stays in VGPRs)
  auto tile = [&](int t, int cur) {
    ldA(a0, cur, 0); ldB(b0, cur, 0);
    stB(t + 1, cur ^ 1, 1);
    BARR(); LGKM0();
    mmaq(a0, b0, 0, 0);
    BARR();
    ldB(b1, cur, 1);
    BARR(); LGKM0();
    mmaq(a0, b1, 0, 1);
    if constexpr (RS) mmars(a0, 0);
    BARR();
    ldA(a1, cur, 1);
    stB(t + 2, cur, 0);
    BARR(); LGKM0();
    mmaq(a1, b1, 1, 1);
    BARR();
    stA(t + 2, cur);
    BARR();
    mmaq(a1, b0, 1, 0);
    if constexpr (RS) mmars(a1, 1);
    VMC6();   // retire tile t+1's 8 loads; keep tile t+2's 6 in flight
    BARR();
  };

#pragma unroll
  for (int rep = 0; rep < REPS; ++rep) {
    const int tb = rep << NTL;
    for (int tt = 0; tt < NT; tt += 2) {
      tile(tb + tt, 0);
      tile(tb + tt + 1, 1);
    }

    // ---------- per-rep epilogue: STRAIGHT INLINE CODE (no call) --------------
    {
      int zz2, bm2, bn2;
      const float* biasp;
      void* Cvp;
      bool tr = false;
      if constexpr (QKV3) {
        zz2 = 0; bm2 = bmr0; bn2 = bnr0;
        biasp = rep == 0 ? bias : (rep == 1 ? bias1 : bias2);
        Cvp   = rep == 0 ? Cv   : (rep == 1 ? Cv1   : Cv2);
        tr = (rep == 2);
      } else {
        zz2 = (REPS >= 2 && rep) ? zzr1 : zzr0;
        bm2 = (REPS >= 2 && rep) ? bmr1 : bmr0;
        bn2 = (REPS >= 2 && rep) ? bnr1 : bnr0;
        biasp = bias; Cvp = Cv;
      }
      const int colb = bn2 * 128 + wn * 64 + l15;
      const int rowb = bm2 * 128 + wm * 64 + lq * 4;
#pragma unroll
      for (int m = 0; m < 4; ++m) {
        float inv[4];
        if constexpr (RS) {
#pragma unroll
          for (int j = 0; j < 4; ++j) inv[j] = 1.0f / rs[m][j];
        }
#pragma unroll
        for (int n = 0; n < 4; ++n) {
          const int colg = colb + n * 16;
          float bval = 0.0f;
          if constexpr (OUTMODE != 3) bval = biasp ? biasp[colg] : 0.0f;
          if (QKV3 && tr) {
            const int r0 = rowb + m * 16;
            bf16x4 pk;
#pragma unroll
            for (int j = 0; j < 4; ++j) pk[j] = (bf16_t)(acc[m][n][j] * scale + bval);
            const long bb = (long)(r0 >> 11);
            const int ss = r0 & (SEQ - 1);
            *(bf16x4*)((bf16_t*)Cvp + bb * ((long)E_DIM * SEQ) + (long)colg * SEQ + ss) = pk;
          } else {
#pragma unroll
            for (int j = 0; j < 4; ++j) {
              const int r = rowb + m * 16 + j;
              float v;
              if constexpr (OUTMODE == 3) v = __expf(acc[m][n][j] * scale);
              else v = acc[m][n][j] * scale + bval;
              if constexpr (RS) v *= inv[j];
              if (OUTMODE == 0 && residual) v += residual[(long)r * ldc + colg];
              const long idx = (long)zz2 * sC + (long)r * ldc + colg;
              if constexpr (OUTMODE == 0) ((float*)Cvp)[idx] = v;
              else ((bf16_t*)Cvp)[idx] = (bf16_t)v;
            }
          }
        }
      }
      if (rep + 1 < REPS) {
#pragma unroll
        for (int m = 0; m < 4; ++m) {
#pragma unroll
          for (int n = 0; n < 4; ++n) acc[m][n] = (f32x4){0.f, 0.f, 0.f, 0.f};
          rs[m] = (f32x4){0.f, 0.f, 0.f, 0.f};
        }
      }
    }
  }
  VMC0();
#undef GLL
}

// ---------------- layernorm in-place on rows of 1024 f32 ----------------
__global__ __launch_bounds__(256) void k_layernorm(float* __restrict__ out,
                                                   const float* __restrict__ gamma,
                                                   const float* __restrict__ beta) {
  const long row = blockIdx.x;
  float* rp = out + row * 1024;
  const int t = threadIdx.x;
  const float4 v = *(const float4*)(rp + t * 4);
  float s = v.x + v.y + v.z + v.w;
#pragma unroll
  for (int o = 32; o; o >>= 1) s += __shfl_xor(s, o);
  __shared__ float red1[4], red2[4];
  const int lane = t & 63, w = t >> 6;
  if (lane == 0) red1[w] = s;
  __syncthreads();
  const float mu = (red1[0] + red1[1] + red1[2] + red1[3]) * (1.0f / 1024.0f);
  const float d0 = v.x - mu, d1 = v.y - mu, d2 = v.z - mu, d3 = v.w - mu;
  float ss = d0 * d0 + d1 * d1 + d2 * d2 + d3 * d3;
#pragma unroll
  for (int o = 32; o; o >>= 1) ss += __shfl_xor(ss, o);
  if (lane == 0) red2[w] = ss;
  __syncthreads();
  const float var = (red2[0] + red2[1] + red2[2] + red2[3]) * (1.0f / 1024.0f);
  const float rsq = rsqrtf(var + 1e-6f);
  const float4 g = *(const float4*)(gamma + t * 4);
  const float4 b = *(const float4*)(beta + t * 4);
  float4 o;
  o.x = d0 * rsq * g.x + b.x;
  o.y = d1 * rsq * g.y + b.y;
  o.z = d2 * rsq * g.z + b.z;
  o.w = d3 * rsq * g.w + b.w;
  *(float4*)(rp + t * 4) = o;
}

extern "C" void kernel_launch(void* const* d_in, const int* in_sizes, int n_in,
                              void* d_out, int out_size, void* d_ws, size_t ws_size,
                              hipStream_t stream) {
  const float* query = (const float*)d_in[0];
  const float* key   = (const float*)d_in[1];
  const float* value = (const float*)d_in[2];
  const float* Wq = (const float*)d_in[3];
  const float* bq = (const float*)d_in[4];
  const float* Wk = (const float*)d_in[5];
  const float* bk = (const float*)d_in[6];
  const float* Wv = (const float*)d_in[7];
  const float* bv = (const float*)d_in[8];
  const float* Wo = (const float*)d_in[9];
  const float* bo = (const float*)d_in[10];
  const float* gamma = (const float*)d_in[11];
  const float* beta  = (const float*)d_in[12];
  float* out = (float*)d_out;

  char* ws = (char*)d_ws;
  const size_t XSZ = (size_t)NBATCH * SEQ * E_DIM * 2;  // 16 MiB
  const size_t WSZ = (size_t)E_DIM * E_DIM * 2;         // 2 MiB
  const size_t B2  = 3 * XSZ;                           // 48 MiB boundary

  bf16_t* Xq  = (bf16_t*)(ws + 0);
  bf16_t* Xk  = (bf16_t*)(ws + XSZ);
  bf16_t* Xv  = (bf16_t*)(ws + 2 * XSZ);
  bf16_t* SC  = (bf16_t*)(ws + 0);   // exp-scores overlay dead X buffers (33.5MB<48)
  bf16_t* Wqb = (bf16_t*)(ws + B2);
  bf16_t* Wkb = (bf16_t*)(ws + B2 + WSZ);
  bf16_t* Wvb = (bf16_t*)(ws + B2 + 2 * WSZ);
  bf16_t* Wob = (bf16_t*)(ws + B2 + 3 * WSZ);
  bf16_t* Qb  = (bf16_t*)(ws + B2 + 4 * WSZ);
  bf16_t* Kb  = (bf16_t*)(ws + B2 + 4 * WSZ + XSZ);
  bf16_t* Vt  = (bf16_t*)(ws + B2 + 4 * WSZ + 2 * XSZ);
  bf16_t* Ctx = (bf16_t*)(ws + B2 + 4 * WSZ + 3 * XSZ);

  const int NTOK = NBATCH * SEQ;  // 8192
  const int SMB = 65536;          // 2 x 32KB -> 2 wg/CU

  hipFuncSetAttribute((const void*)k_g13<1, false, true, 3, 4>, hipFuncAttributeMaxDynamicSharedMemorySize, SMB);
  hipFuncSetAttribute((const void*)k_g13<3, false, false, 2, 4>, hipFuncAttributeMaxDynamicSharedMemorySize, SMB);
  hipFuncSetAttribute((const void*)k_g13<1, true, false, 1, 5>, hipFuncAttributeMaxDynamicSharedMemorySize, SMB);
  hipFuncSetAttribute((const void*)k_g13<0, false, false, 1, 4>, hipFuncAttributeMaxDynamicSharedMemorySize, SMB);

  // 1) casts
  k_cast_all<<<dim3(14336), 256, 0, stream>>>(query, key, value, Wq, Wk, Wv, Wo,
                                              Xq, Xk, Xv, Wqb, Wkb, Wvb, Wob);

  // 2) persistent merged Q/K/V projections: grid 512, REPS=3 slabs per wg
  k_g13<1, false, true, 3, 4><<<512, 256, SMB, stream>>>(
      Xq, E_DIM, 0, Wqb, E_DIM, 0, Qb, E_DIM, 0, 1.0f, bq, nullptr, 64, 8,
      Xk, Xv, Wkb, Wvb, bk, bv, Kb, Vt);

  // 3) P = exp(Q K^T / 32): grid 512, REPS=2 (16x16x4 = 1024 tiles)
  k_g13<3, false, false, 2, 4><<<512, 256, SMB, stream>>>(
      Qb, E_DIM, (long)SEQ * E_DIM, Kb, E_DIM, (long)SEQ * E_DIM,
      SC, SEQ, (long)SEQ * SEQ, 0.03125f, nullptr, nullptr, 16, 16,
      nullptr, nullptr, nullptr, nullptr, nullptr, nullptr, nullptr, nullptr);

  // 4) ctx = (P @ V) / rowsum: grid 512, REPS=1, NT=32
  k_g13<1, true, false, 1, 5><<<512, 256, SMB, stream>>>(
      SC, SEQ, (long)SEQ * SEQ, Vt, SEQ, (long)E_DIM * SEQ,
      Ctx, E_DIM, (long)SEQ * E_DIM, 1.0f, nullptr, nullptr, 16, 8,
      nullptr, nullptr, nullptr, nullptr, nullptr, nullptr, nullptr, nullptr);

  // 5) out = ctx Wo^T + bo + residual(query): grid 512, REPS=1
  k_g13<0, false, false, 1, 4><<<512, 256, SMB, stream>>>(
      Ctx, E_DIM, 0, Wob, E_DIM, 0, out, E_DIM, 0, 1.0f, bo, query, 64, 8,
      nullptr, nullptr, nullptr, nullptr, nullptr, nullptr, nullptr, nullptr);

  // 6) layernorm in-place
  k_layernorm<<<dim3(NTOK), 256, 0, stream>>>(out, gamma, beta);
}

// Round 14
// 224.896 us; speedup vs baseline: 3.2275x; 1.0012x over previous
//
#include <hip/hip_runtime.h>
#include <hip/hip_bf16.h>

typedef __bf16 bf16_t;
typedef __bf16 bf16x4 __attribute__((ext_vector_type(4)));
typedef __bf16 bf16x8 __attribute__((ext_vector_type(8)));
typedef float f32x4 __attribute__((ext_vector_type(4)));

#define E_DIM 1024
#define SEQ   2048
#define NBATCH 4

#define BARR()  asm volatile("s_barrier" ::: "memory")
#define LGKM0() asm volatile("s_waitcnt lgkmcnt(0)" ::: "memory")
#define VMC6()  asm volatile("s_waitcnt vmcnt(6)" ::: "memory")
#define VMC2()  asm volatile("s_waitcnt vmcnt(2)" ::: "memory")
#define VMC0()  asm volatile("s_waitcnt vmcnt(0)" ::: "memory")

// ---------------- weight casts only (4 x 1024x1024 f32 -> bf16) ----------------
__global__ __launch_bounds__(256) void k_castw(
    const float* __restrict__ wq, const float* __restrict__ wk,
    const float* __restrict__ wv, const float* __restrict__ wo,
    bf16_t* __restrict__ wqb, bf16_t* __restrict__ wkb,
    bf16_t* __restrict__ wvb, bf16_t* __restrict__ wob) {
  const int b = blockIdx.x;
  const int w = b >> 9, r = b & 511;
  const float* s = (w == 0) ? wq : (w == 1) ? wk : (w == 2) ? wv : wo;
  bf16_t* d = (w == 0) ? wqb : (w == 1) ? wkb : (w == 2) ? wvb : wob;
  const long i = (long)r * 2048 + threadIdx.x * 8;
  const f32x4 a = *(const f32x4*)(s + i);
  const f32x4 c = *(const f32x4*)(s + i + 4);
  bf16x8 o;
  o[0] = (bf16_t)a[0]; o[1] = (bf16_t)a[1]; o[2] = (bf16_t)a[2]; o[3] = (bf16_t)a[3];
  o[4] = (bf16_t)c[0]; o[5] = (bf16_t)c[1]; o[6] = (bf16_t)c[2]; o[7] = (bf16_t)c[3];
  *(bf16x8*)(d + i) = o;
}

// =================================================================================
// PERSISTENT 4-phase GEMM v4.  Round-13 core; adds AF32: A staged DIRECTLY from
// f32 input (T14 reg-stage: 8 x global_load_dwordx4 -> cvt -> 4 swizzled
// ds_write_b128), eliminating the X f32->bf16 cast round-trip (saves 96MB HBM +
// most of the cast dispatch).  Swizzle moves to the WRITE address; global read
// is linear.  New ledger (AF32), issue order per tile [stB_h1 x2, La x8,
// stB_h0 x2]: ph3 VMC2 retires La(t+2) + all B(t+1), keeps stB(t+2,h0) x2.
// ds_write hazards: A(cur) readers finish at mid-ph2 LGKM0 (before ph2-end
// barrier); writer runs after it; writes published via LGKM0 before final BARR.
// Tile body is a MACRO (r11/r12 lesson: lambda inline-threshold -> scratch).
// Non-AF32 instantiations compile to the round-13 path unchanged.
// Tile 128x128, BK=64, 4 waves (2x2), per-wave 64x64, mfma_f32_16x16x32_bf16,
// conflict-free XOR-8 LDS swizzle, 2x32KB LDS (2 wg/CU), counted vmcnt.
// OUTMODE 0:f32+bias+residual, 1:bf16+bias, 3:bf16 exp(v*scale).
// RS: ones-MFMA rowsum (lane-local), rows scaled by 1/rs (PV normalize).
// QKV3: REPS=3 slabs (Q,K,V) at same (bm,bn); slab 2 stores transposed Vt.
// =================================================================================
template <int OUTMODE, bool RS, bool QKV3, int REPS, int NTL, bool AF32>
__global__ __launch_bounds__(256, 2) void k_g14(
    const void* __restrict__ A, int lda, long sA,
    const bf16_t* __restrict__ B, int ldb, long sB,
    void* __restrict__ Cv, int ldc, long sC,
    float scale, const float* __restrict__ bias,
    const float* __restrict__ residual, int GM, int GN,
    const void* __restrict__ A1, const void* __restrict__ A2,
    const bf16_t* __restrict__ B1, const bf16_t* __restrict__ B2,
    const float* __restrict__ bias1, const float* __restrict__ bias2,
    void* __restrict__ Cv1, void* __restrict__ Cv2) {
  constexpr int ASZ   = 16384;           // A tile bytes (128 x 64 bf16)
  constexpr int BUFSZ = 32768;           // A + B per buffer
  constexpr int NT    = 1 << NTL;        // K-tiles per output tile
  constexpr int TT    = REPS << NTL;     // total K-tiles per wg
  extern __shared__ char smem[];

  const int tid  = threadIdx.x;
  const int lane = tid & 63;
  const int wid  = tid >> 6;
  const int wm   = wid >> 1;             // 0..1
  const int wn   = wid & 1;              // 0..1
  const int l15  = lane & 15;
  const int lq   = lane >> 4;            // k-chunk 0..3

  // T1: XCD swizzle (grids are multiples of 8)
  const int nwg  = gridDim.x;
  const int orig = blockIdx.x;
  const int wg   = (orig & 7) * (nwg >> 3) + (orig >> 3);

  const int colk = ((tid & 7) ^ ((tid >> 3) & 7)) << 3;  // bf16-GLL inverse swizzle
  const int trow = tid >> 3;
  const int ldsw = wid << 10;            // 4 waves x 1KB = one 4KB (32-row) unit

  // -------- per-rep NAMED bases (ternary selection only; rule-#20-safe) -------
  const bf16_t *pA0 = nullptr, *pA1 = nullptr, *pA2 = nullptr;
  const float  *pAf0 = nullptr, *pAf1 = nullptr, *pAf2 = nullptr;
  const bf16_t *pB0, *pB1 = nullptr, *pB2 = nullptr;
  int zzr0 = 0, bmr0 = 0, bnr0 = 0, zzr1 = 0, bmr1 = 0, bnr1 = 0;
  if constexpr (QKV3) {
    bmr0 = wg / GN; bnr0 = wg - bmr0 * GN;
    const long boff = (long)(bnr0 * 128 + trow) * ldb + colk;
    pB0 = B + boff;  pB1 = B1 + boff;  pB2 = B2 + boff;
    if constexpr (AF32) {
      const long aoff = (long)(bmr0 * 128 + trow) * lda + (tid & 7) * 8;  // linear f32
      pAf0 = (const float*)A + aoff;  pAf1 = (const float*)A1 + aoff;
      pAf2 = (const float*)A2 + aoff;
    } else {
      const long aoff = (long)(bmr0 * 128 + trow) * lda + colk;
      pA0 = (const bf16_t*)A + aoff;  pA1 = (const bf16_t*)A1 + aoff;
      pA2 = (const bf16_t*)A2 + aoff;
    }
  } else {
    {
      const int g  = wg;
      zzr0 = g / (GM * GN);
      const int rm = g - zzr0 * (GM * GN);
      bmr0 = rm / GN; bnr0 = rm - bmr0 * GN;
      pA0 = (const bf16_t*)A + zzr0 * sA + (long)(bmr0 * 128 + trow) * lda + colk;
      pB0 = B + zzr0 * sB + (long)(bnr0 * 128 + trow) * ldb + colk;
    }
    if constexpr (REPS >= 2) {
      const int g  = nwg + wg;
      zzr1 = g / (GM * GN);
      const int rm = g - zzr1 * (GM * GN);
      bmr1 = rm / GN; bnr1 = rm - bmr1 * GN;
      pA1 = (const bf16_t*)A + zzr1 * sA + (long)(bmr1 * 128 + trow) * lda + colk;
      pB1 = B + zzr1 * sB + (long)(bnr1 * 128 + trow) * ldb + colk;
    }
  }

#define GLL(gaddr, ldsoff)                                                       \
  __builtin_amdgcn_global_load_lds(                                             \
      (const __attribute__((address_space(1))) void*)(gaddr),                   \
      (__attribute__((address_space(3))) void*)(smem + (ldsoff)), 16, 0, 0)

  auto stA = [&](int tau, int buf) {           // bf16 path: 4 x 4KB GLL units
    if constexpr (!AF32) {
      tau = tau < TT ? tau : TT - 1;
      const int rep = tau >> NTL;
      const bf16_t* p = (REPS == 1) ? pA0
                      : (REPS == 2) ? (rep ? pA1 : pA0)
                      : (rep == 0 ? pA0 : (rep == 1 ? pA1 : pA2));
      p += (long)(tau & (NT - 1)) * 64;
#pragma unroll
      for (int s = 0; s < 4; ++s)
        GLL(p + (long)(s * 32) * lda, buf * BUFSZ + s * 4096 + ldsw);
    }
  };
  auto stB = [&](int tau, int buf, int half) { // B half: 2 x 4KB units
    tau = tau < TT ? tau : TT - 1;
    const int rep = tau >> NTL;
    const bf16_t* p = (REPS == 1) ? pB0
                    : (REPS == 2) ? (rep ? pB1 : pB0)
                    : (rep == 0 ? pB0 : (rep == 1 ? pB1 : pB2));
    p += (long)(tau & (NT - 1)) * 64;
#pragma unroll
    for (int s = 0; s < 2; ++s)
      GLL(p + (long)(half * 64 + s * 32) * ldb,
          buf * BUFSZ + ASZ + half * 8192 + s * 4096 + ldsw);
  };

  // -------- AF32 A-path: reg-stage f32 -> cvt -> swizzled ds_write ------------
  f32x4 a32[8];                                // constant-indexed only
  int wbyt[4];
#pragma unroll
  for (int s = 0; s < 4; ++s) {
    const int row = s * 32 + trow;
    wbyt[s] = row * 128 + (((tid & 7) * 16) ^ ((row & 7) << 4));
  }
  auto ldAg = [&](int tau) {                   // issue 8 f32 loads for tile tau
    if constexpr (AF32) {
      tau = tau < TT ? tau : TT - 1;
      const int rep = tau >> NTL;
      const float* p = (REPS == 1) ? pAf0
                     : (REPS == 2) ? (rep ? pAf1 : pAf0)
                     : (rep == 0 ? pAf0 : (rep == 1 ? pAf1 : pAf2));
      p += (long)(tau & (NT - 1)) * 64;
#pragma unroll
      for (int s = 0; s < 4; ++s) {
        a32[2 * s]     = *(const f32x4*)(p + (long)(s * 32) * lda);
        a32[2 * s + 1] = *(const f32x4*)(p + (long)(s * 32) * lda + 4);
      }
    }
  };
  auto wrA = [&](int buf) {                    // cvt + 4 swizzled ds_write_b128
    if constexpr (AF32) {
#pragma unroll
      for (int s = 0; s < 4; ++s) {
        bf16x8 w;
#pragma unroll
        for (int j = 0; j < 4; ++j) {
          w[j]     = (bf16_t)a32[2 * s][j];
          w[4 + j] = (bf16_t)a32[2 * s + 1][j];
        }
        *(bf16x8*)(smem + buf * BUFSZ + wbyt[s]) = w;
      }
    }
  };

  f32x4 acc[4][4];
#pragma unroll
  for (int m = 0; m < 4; ++m)
#pragma unroll
    for (int n = 0; n < 4; ++n) acc[m][n] = (f32x4){0.f, 0.f, 0.f, 0.f};
  f32x4 rs[4];
#pragma unroll
  for (int m = 0; m < 4; ++m) rs[m] = (f32x4){0.f, 0.f, 0.f, 0.f};
  bf16x8 vones;
#pragma unroll
  for (int i = 0; i < 8; ++i) vones[i] = (bf16_t)1.0f;

  // ds_read fragment loaders (swizzled, conflict-free)
  auto ldA = [&](bf16x8 (&a)[2][2], int cur, int mq) {
#pragma unroll
    for (int i = 0; i < 2; ++i) {
      const int row = wm * 64 + (mq * 2 + i) * 16 + l15;
#pragma unroll
      for (int kk = 0; kk < 2; ++kk) {
        const int byt = cur * BUFSZ + row * 128 + ((kk * 64 + lq * 16) ^ ((row & 7) << 4));
        a[i][kk] = *(const bf16x8*)(smem + byt);
      }
    }
  };
  auto ldB = [&](bf16x8 (&b)[2][2], int cur, int nq) {
#pragma unroll
    for (int n2 = 0; n2 < 2; ++n2) {
      const int row = wn * 64 + (nq * 2 + n2) * 16 + l15;
#pragma unroll
      for (int kk = 0; kk < 2; ++kk) {
        const int byt = cur * BUFSZ + ASZ + row * 128 + ((kk * 64 + lq * 16) ^ ((row & 7) << 4));
        b[n2][kk] = *(const bf16x8*)(smem + byt);
      }
    }
  };
  auto mmaq = [&](bf16x8 (&a)[2][2], bf16x8 (&b)[2][2], int mq, int nq) {
    __builtin_amdgcn_s_setprio(1);
#pragma unroll
    for (int kk = 0; kk < 2; ++kk)
#pragma unroll
      for (int i = 0; i < 2; ++i)
#pragma unroll
        for (int n2 = 0; n2 < 2; ++n2)
          acc[mq * 2 + i][nq * 2 + n2] = __builtin_amdgcn_mfma_f32_16x16x32_bf16(
              a[i][kk], b[n2][kk], acc[mq * 2 + i][nq * 2 + n2], 0, 0, 0);
    __builtin_amdgcn_s_setprio(0);
  };
  auto mmars = [&](bf16x8 (&a)[2][2], int mq) {
#pragma unroll
    for (int kk = 0; kk < 2; ++kk)
#pragma unroll
      for (int i = 0; i < 2; ++i)
        rs[mq * 2 + i] = __builtin_amdgcn_mfma_f32_16x16x32_bf16(
            a[i][kk], vones, rs[mq * 2 + i], 0, 0, 0);
  };

  // ---------------- prologue ----------------------------------------------------
  if constexpr (AF32) {
    stB(0, 0, 0); stB(0, 0, 1);
    ldAg(0);
    VMC0();          // A(0) in regs (and B(0) landed)
    wrA(0);
    ldAg(1);
    stB(1, 1, 0);
    VMC2();          // keep stB(1,h0)x2; A(1) in regs
    wrA(1);
    LGKM0();         // publish ds_writes
    BARR();
  } else {
    stB(0, 0, 0); stB(0, 0, 1); stA(0, 0);
    stB(1, 1, 0); stA(1, 1);
    VMC6();          // 14 outstanding -> retire tile0's 8, keep t1's 6
    BARR();
  }

  bf16x8 a0[2][2], a1[2][2], b0[2][2], b1[2][2];

// tile body as MACRO: guaranteed "inline", acc stays in VGPRs (r11/r12 lesson)
#define TILE_STEP(t_, cur_)                                                     \
  {                                                                             \
    ldA(a0, (cur_), 0); ldB(b0, (cur_), 0);                                     \
    stB((t_) + 1, (cur_) ^ 1, 1);                                               \
    if constexpr (AF32) ldAg((t_) + 2);                                         \
    BARR(); LGKM0();                                                            \
    mmaq(a0, b0, 0, 0);                                                         \
    BARR();                                                                     \
    ldB(b1, (cur_), 1);                                                         \
    BARR(); LGKM0();                                                            \
    mmaq(a0, b1, 0, 1);                                                         \
    if constexpr (RS) mmars(a0, 0);                                             \
    BARR();                                                                     \
    ldA(a1, (cur_), 1);                                                         \
    stB((t_) + 2, (cur_), 0);                                                   \
    BARR(); LGKM0();                                                            \
    mmaq(a1, b1, 1, 1);                                                         \
    BARR();                                                                     \
    if constexpr (!AF32) stA((t_) + 2, (cur_));                                 \
    BARR();                                                                     \
    mmaq(a1, b0, 1, 0);                                                         \
    if constexpr (RS) mmars(a1, 1);                                             \
    if constexpr (AF32) { VMC2(); wrA((cur_)); LGKM0(); }                       \
    else VMC6();                                                                \
    BARR();                                                                     \
  }

#pragma unroll
  for (int rep = 0; rep < REPS; ++rep) {
    const int tb = rep << NTL;
    for (int tt = 0; tt < NT; tt += 2) {
      TILE_STEP(tb + tt, 0)
      TILE_STEP(tb + tt + 1, 1)
    }

    // ---------- per-rep epilogue: STRAIGHT INLINE CODE (no call) --------------
    {
      int zz2, bm2, bn2;
      const float* biasp;
      void* Cvp;
      bool tr = false;
      if constexpr (QKV3) {
        zz2 = 0; bm2 = bmr0; bn2 = bnr0;
        biasp = rep == 0 ? bias : (rep == 1 ? bias1 : bias2);
        Cvp   = rep == 0 ? Cv   : (rep == 1 ? Cv1   : Cv2);
        tr = (rep == 2);
      } else {
        zz2 = (REPS >= 2 && rep) ? zzr1 : zzr0;
        bm2 = (REPS >= 2 && rep) ? bmr1 : bmr0;
        bn2 = (REPS >= 2 && rep) ? bnr1 : bnr0;
        biasp = bias; Cvp = Cv;
      }
      const int colb = bn2 * 128 + wn * 64 + l15;
      const int rowb = bm2 * 128 + wm * 64 + lq * 4;
#pragma unroll
      for (int m = 0; m < 4; ++m) {
        float inv[4];
        if constexpr (RS) {
#pragma unroll
          for (int j = 0; j < 4; ++j) inv[j] = 1.0f / rs[m][j];
        }
#pragma unroll
        for (int n = 0; n < 4; ++n) {
          const int colg = colb + n * 16;
          float bval = 0.0f;
          if constexpr (OUTMODE != 3) bval = biasp ? biasp[colg] : 0.0f;
          if (QKV3 && tr) {
            const int r0 = rowb + m * 16;
            bf16x4 pk;
#pragma unroll
            for (int j = 0; j < 4; ++j) pk[j] = (bf16_t)(acc[m][n][j] * scale + bval);
            const long bb = (long)(r0 >> 11);
            const int ss = r0 & (SEQ - 1);
            *(bf16x4*)((bf16_t*)Cvp + bb * ((long)E_DIM * SEQ) + (long)colg * SEQ + ss) = pk;
          } else {
#pragma unroll
            for (int j = 0; j < 4; ++j) {
              const int r = rowb + m * 16 + j;
              float v;
              if constexpr (OUTMODE == 3) v = __expf(acc[m][n][j] * scale);
              else v = acc[m][n][j] * scale + bval;
              if constexpr (RS) v *= inv[j];
              if (OUTMODE == 0 && residual) v += residual[(long)r * ldc + colg];
              const long idx = (long)zz2 * sC + (long)r * ldc + colg;
              if constexpr (OUTMODE == 0) ((float*)Cvp)[idx] = v;
              else ((bf16_t*)Cvp)[idx] = (bf16_t)v;
            }
          }
        }
      }
      if (rep + 1 < REPS) {
#pragma unroll
        for (int m = 0; m < 4; ++m) {
#pragma unroll
          for (int n = 0; n < 4; ++n) acc[m][n] = (f32x4){0.f, 0.f, 0.f, 0.f};
          rs[m] = (f32x4){0.f, 0.f, 0.f, 0.f};
        }
      }
    }
  }
  VMC0();
#undef TILE_STEP
#undef GLL
}

// ---------------- layernorm in-place on rows of 1024 f32 ----------------
__global__ __launch_bounds__(256) void k_layernorm(float* __restrict__ out,
                                                   const float* __restrict__ gamma,
                                                   const float* __restrict__ beta) {
  const long row = blockIdx.x;
  float* rp = out + row * 1024;
  const int t = threadIdx.x;
  const float4 v = *(const float4*)(rp + t * 4);
  float s = v.x + v.y + v.z + v.w;
#pragma unroll
  for (int o = 32; o; o >>= 1) s += __shfl_xor(s, o);
  __shared__ float red1[4], red2[4];
  const int lane = t & 63, w = t >> 6;
  if (lane == 0) red1[w] = s;
  __syncthreads();
  const float mu = (red1[0] + red1[1] + red1[2] + red1[3]) * (1.0f / 1024.0f);
  const float d0 = v.x - mu, d1 = v.y - mu, d2 = v.z - mu, d3 = v.w - mu;
  float ss = d0 * d0 + d1 * d1 + d2 * d2 + d3 * d3;
#pragma unroll
  for (int o = 32; o; o >>= 1) ss += __shfl_xor(ss, o);
  if (lane == 0) red2[w] = ss;
  __syncthreads();
  const float var = (red2[0] + red2[1] + red2[2] + red2[3]) * (1.0f / 1024.0f);
  const float rsq = rsqrtf(var + 1e-6f);
  const float4 g = *(const float4*)(gamma + t * 4);
  const float4 b = *(const float4*)(beta + t * 4);
  float4 o;
  o.x = d0 * rsq * g.x + b.x;
  o.y = d1 * rsq * g.y + b.y;
  o.z = d2 * rsq * g.z + b.z;
  o.w = d3 * rsq * g.w + b.w;
  *(float4*)(rp + t * 4) = o;
}

extern "C" void kernel_launch(void* const* d_in, const int* in_sizes, int n_in,
                              void* d_out, int out_size, void* d_ws, size_t ws_size,
                              hipStream_t stream) {
  const float* query = (const float*)d_in[0];
  const float* key   = (const float*)d_in[1];
  const float* value = (const float*)d_in[2];
  const float* Wq = (const float*)d_in[3];
  const float* bq = (const float*)d_in[4];
  const float* Wk = (const float*)d_in[5];
  const float* bk = (const float*)d_in[6];
  const float* Wv = (const float*)d_in[7];
  const float* bv = (const float*)d_in[8];
  const float* Wo = (const float*)d_in[9];
  const float* bo = (const float*)d_in[10];
  const float* gamma = (const float*)d_in[11];
  const float* beta  = (const float*)d_in[12];
  float* out = (float*)d_out;

  char* ws = (char*)d_ws;
  const size_t XSZ = (size_t)NBATCH * SEQ * E_DIM * 2;  // 16 MiB
  const size_t WSZ = (size_t)E_DIM * E_DIM * 2;         // 2 MiB
  const size_t B2  = 3 * XSZ;                           // 48 MiB boundary

  bf16_t* SC  = (bf16_t*)(ws + 0);            // exp-scores, 33.5 MB
  bf16_t* Wqb = (bf16_t*)(ws + B2);
  bf16_t* Wkb = (bf16_t*)(ws + B2 + WSZ);
  bf16_t* Wvb = (bf16_t*)(ws + B2 + 2 * WSZ);
  bf16_t* Wob = (bf16_t*)(ws + B2 + 3 * WSZ);
  bf16_t* Qb  = (bf16_t*)(ws + B2 + 4 * WSZ);
  bf16_t* Kb  = (bf16_t*)(ws + B2 + 4 * WSZ + XSZ);
  bf16_t* Vt  = (bf16_t*)(ws + B2 + 4 * WSZ + 2 * XSZ);
  bf16_t* Ctx = (bf16_t*)(ws + B2 + 4 * WSZ + 3 * XSZ);

  const int NTOK = NBATCH * SEQ;  // 8192
  const int SMB = 65536;          // 2 x 32KB -> 2 wg/CU

  hipFuncSetAttribute((const void*)k_g14<1, false, true, 3, 4, true>,  hipFuncAttributeMaxDynamicSharedMemorySize, SMB);
  hipFuncSetAttribute((const void*)k_g14<3, false, false, 2, 4, false>, hipFuncAttributeMaxDynamicSharedMemorySize, SMB);
  hipFuncSetAttribute((const void*)k_g14<1, true, false, 1, 5, false>,  hipFuncAttributeMaxDynamicSharedMemorySize, SMB);
  hipFuncSetAttribute((const void*)k_g14<0, false, false, 1, 4, false>, hipFuncAttributeMaxDynamicSharedMemorySize, SMB);

  // 1) weight casts only (X consumed f32 directly by the AF32 QKV kernel)
  k_castw<<<dim3(2048), 256, 0, stream>>>(Wq, Wk, Wv, Wo, Wqb, Wkb, Wvb, Wob);

  // 2) persistent merged Q/K/V projections, f32 A reg-staged: grid 512, REPS=3
  k_g14<1, false, true, 3, 4, true><<<512, 256, SMB, stream>>>(
      query, E_DIM, 0, Wqb, E_DIM, 0, Qb, E_DIM, 0, 1.0f, bq, nullptr, 64, 8,
      key, value, Wkb, Wvb, bk, bv, Kb, Vt);

  // 3) P = exp(Q K^T / 32): grid 512, REPS=2 (16x16x4 = 1024 tiles)
  k_g14<3, false, false, 2, 4, false><<<512, 256, SMB, stream>>>(
      Qb, E_DIM, (long)SEQ * E_DIM, Kb, E_DIM, (long)SEQ * E_DIM,
      SC, SEQ, (long)SEQ * SEQ, 0.03125f, nullptr, nullptr, 16, 16,
      nullptr, nullptr, nullptr, nullptr, nullptr, nullptr, nullptr, nullptr);

  // 4) ctx = (P @ V) / rowsum: grid 512, REPS=1, NT=32
  k_g14<1, true, false, 1, 5, false><<<512, 256, SMB, stream>>>(
      SC, SEQ, (long)SEQ * SEQ, Vt, SEQ, (long)E_DIM * SEQ,
      Ctx, E_DIM, (long)SEQ * E_DIM, 1.0f, nullptr, nullptr, 16, 8,
      nullptr, nullptr, nullptr, nullptr, nullptr, nullptr, nullptr, nullptr);

  // 5) out = ctx Wo^T + bo + residual(query): grid 512, REPS=1
  k_g14<0, false, false, 1, 4, false><<<512, 256, SMB, stream>>>(
      Ctx, E_DIM, 0, Wob, E_DIM, 0, out, E_DIM, 0, 1.0f, bo, query, 64, 8,
      nullptr, nullptr, nullptr, nullptr, nullptr, nullptr, nullptr, nullptr);

  // 6) layernorm in-place
  k_layernorm<<<dim3(NTOK), 256, 0, stream>>>(out, gamma, beta);
}

// Round 15
// 222.565 us; speedup vs baseline: 3.2613x; 1.0105x over previous
//
#include <hip/hip_runtime.h>
#include <hip/hip_bf16.h>

typedef __bf16 bf16_t;
typedef __bf16 bf16x4 __attribute__((ext_vector_type(4)));
typedef __bf16 bf16x8 __attribute__((ext_vector_type(8)));
typedef float f32x4 __attribute__((ext_vector_type(4)));

#define E_DIM 1024
#define SEQ   2048
#define NBATCH 4

#define BARR()  asm volatile("s_barrier" ::: "memory")
#define LGKM0() asm volatile("s_waitcnt lgkmcnt(0)" ::: "memory")
#define VMC6()  asm volatile("s_waitcnt vmcnt(6)" ::: "memory")
#define VMC0()  asm volatile("s_waitcnt vmcnt(0)" ::: "memory")

// ---------------- casts: 16 elems/thread, 4096-elem blocks, per-block segment --
// Block ranges: [0,2048) Xq, [2048,4096) Xk, [4096,6144) Xv,
// [6144,6400) Wq, [6400,6656) Wk, [6656,6912) Wv, [6912,7168) Wo.
__global__ __launch_bounds__(256) void k_cast2(
    const float* __restrict__ q, const float* __restrict__ k, const float* __restrict__ v,
    const float* __restrict__ wq, const float* __restrict__ wk,
    const float* __restrict__ wv, const float* __restrict__ wo,
    bf16_t* __restrict__ xq, bf16_t* __restrict__ xk, bf16_t* __restrict__ xv,
    bf16_t* __restrict__ wqb, bf16_t* __restrict__ wkb,
    bf16_t* __restrict__ wvb, bf16_t* __restrict__ wob) {
  const int b = blockIdx.x;
  const float* s; bf16_t* d; long base;
  if (b < 2048)        { s = q;  d = xq;  base = (long)b * 4096; }
  else if (b < 4096)   { s = k;  d = xk;  base = (long)(b - 2048) * 4096; }
  else if (b < 6144)   { s = v;  d = xv;  base = (long)(b - 4096) * 4096; }
  else if (b < 6400)   { s = wq; d = wqb; base = (long)(b - 6144) * 4096; }
  else if (b < 6656)   { s = wk; d = wkb; base = (long)(b - 6400) * 4096; }
  else if (b < 6912)   { s = wv; d = wvb; base = (long)(b - 6656) * 4096; }
  else                 { s = wo; d = wob; base = (long)(b - 6912) * 4096; }
  const long i = base + threadIdx.x * 16;
  const f32x4 a0 = *(const f32x4*)(s + i);
  const f32x4 a1 = *(const f32x4*)(s + i + 4);
  const f32x4 a2 = *(const f32x4*)(s + i + 8);
  const f32x4 a3 = *(const f32x4*)(s + i + 12);
  bf16x8 o0, o1;
#pragma unroll
  for (int j = 0; j < 4; ++j) {
    o0[j] = (bf16_t)a0[j]; o0[4 + j] = (bf16_t)a1[j];
    o1[j] = (bf16_t)a2[j]; o1[4 + j] = (bf16_t)a3[j];
  }
  *(bf16x8*)(d + i) = o0;
  *(bf16x8*)(d + i + 8) = o1;
}

// =================================================================================
// PERSISTENT 4-phase GEMM v3 (round-13-verified, byte-identical core).
// Rule-#20-safe persistence: per-rep bases are NAMED scalars via ternaries; rep
// loop top-level unrolled; per-rep epilogue is straight inline code (r11/r12
// lesson: lambda-wrapped epilogue broke inlining -> acc to scratch).
// Tile 128x128, BK=64, 4 waves (2x2), per-wave 64x64, mfma_f32_16x16x32_bf16,
// conflict-free XOR-8 LDS swizzle, 2x32KB LDS (2 wg/CU), counted vmcnt ledger:
// 8 GLL/tile; end-of-tile VMC6 retires tile t+1's 8, keeps t+2's 6 in flight.
// OUTMODE 0:f32+bias+residual, 1:bf16+bias, 3:bf16 exp(v*scale).
// RS: ones-MFMA rowsum (lane-local), rows scaled by 1/rs (PV normalize).
// QKV3: REPS=3 slabs (Q,K,V) at same (bm,bn); slab 2 stores transposed Vt.
// =================================================================================
template <int OUTMODE, bool RS, bool QKV3, int REPS, int NTL>
__global__ __launch_bounds__(256, 2) void k_g13(
    const bf16_t* __restrict__ A, int lda, long sA,
    const bf16_t* __restrict__ B, int ldb, long sB,
    void* __restrict__ Cv, int ldc, long sC,
    float scale, const float* __restrict__ bias,
    const float* __restrict__ residual, int GM, int GN,
    const bf16_t* __restrict__ A1, const bf16_t* __restrict__ A2,
    const bf16_t* __restrict__ B1, const bf16_t* __restrict__ B2,
    const float* __restrict__ bias1, const float* __restrict__ bias2,
    void* __restrict__ Cv1, void* __restrict__ Cv2) {
  constexpr int ASZ   = 16384;           // A tile bytes (128 x 64 bf16)
  constexpr int BUFSZ = 32768;           // A + B per buffer
  constexpr int NT    = 1 << NTL;        // K-tiles per output tile
  constexpr int TT    = REPS << NTL;     // total K-tiles per wg
  extern __shared__ char smem[];

  const int tid  = threadIdx.x;
  const int lane = tid & 63;
  const int wid  = tid >> 6;
  const int wm   = wid >> 1;             // 0..1
  const int wn   = wid & 1;              // 0..1
  const int l15  = lane & 15;
  const int lq   = lane >> 4;            // k-chunk 0..3

  // T1: XCD swizzle (grids are multiples of 8)
  const int nwg  = gridDim.x;
  const int orig = blockIdx.x;
  const int wg   = (orig & 7) * (nwg >> 3) + (orig >> 3);

  // staging source invariants (inverse-swizzled col; rule 21)
  const int colk = ((tid & 7) ^ ((tid >> 3) & 7)) << 3;
  const int trow = tid >> 3;
  const int ldsw = wid << 10;            // 4 waves x 1KB = one 4KB (32-row) unit

  // -------- per-rep NAMED bases (ternary selection only; rule-#20-safe) -------
  const bf16_t *pA0, *pB0, *pA1 = nullptr, *pB1 = nullptr, *pA2 = nullptr, *pB2 = nullptr;
  int zzr0 = 0, bmr0 = 0, bnr0 = 0, zzr1 = 0, bmr1 = 0, bnr1 = 0;
  if constexpr (QKV3) {
    bmr0 = wg / GN; bnr0 = wg - bmr0 * GN;
    const long aoff = (long)(bmr0 * 128 + trow) * lda + colk;
    const long boff = (long)(bnr0 * 128 + trow) * ldb + colk;
    pA0 = A + aoff;  pA1 = A1 + aoff;  pA2 = A2 + aoff;
    pB0 = B + boff;  pB1 = B1 + boff;  pB2 = B2 + boff;
  } else {
    {
      const int g  = wg;
      zzr0 = g / (GM * GN);
      const int rm = g - zzr0 * (GM * GN);
      bmr0 = rm / GN; bnr0 = rm - bmr0 * GN;
      pA0 = A + zzr0 * sA + (long)(bmr0 * 128 + trow) * lda + colk;
      pB0 = B + zzr0 * sB + (long)(bnr0 * 128 + trow) * ldb + colk;
    }
    if constexpr (REPS >= 2) {
      const int g  = nwg + wg;
      zzr1 = g / (GM * GN);
      const int rm = g - zzr1 * (GM * GN);
      bmr1 = rm / GN; bnr1 = rm - bmr1 * GN;
      pA1 = A + zzr1 * sA + (long)(bmr1 * 128 + trow) * lda + colk;
      pB1 = B + zzr1 * sB + (long)(bnr1 * 128 + trow) * ldb + colk;
    }
  }

#define GLL(gaddr, ldsoff)                                                       \
  __builtin_amdgcn_global_load_lds(                                             \
      (const __attribute__((address_space(1))) void*)(gaddr),                   \
      (__attribute__((address_space(3))) void*)(smem + (ldsoff)), 16, 0, 0)

  auto stA = [&](int tau, int buf) {           // full A tile: 4 x 4KB units
    tau = tau < TT ? tau : TT - 1;
    const int rep = tau >> NTL;
    const bf16_t* p = (REPS == 1) ? pA0
                    : (REPS == 2) ? (rep ? pA1 : pA0)
                    : (rep == 0 ? pA0 : (rep == 1 ? pA1 : pA2));
    p += (long)(tau & (NT - 1)) * 64;
#pragma unroll
    for (int s = 0; s < 4; ++s)
      GLL(p + (long)(s * 32) * lda, buf * BUFSZ + s * 4096 + ldsw);
  };
  auto stB = [&](int tau, int buf, int half) { // B half: 2 x 4KB units
    tau = tau < TT ? tau : TT - 1;
    const int rep = tau >> NTL;
    const bf16_t* p = (REPS == 1) ? pB0
                    : (REPS == 2) ? (rep ? pB1 : pB0)
                    : (rep == 0 ? pB0 : (rep == 1 ? pB1 : pB2));
    p += (long)(tau & (NT - 1)) * 64;
#pragma unroll
    for (int s = 0; s < 2; ++s)
      GLL(p + (long)(half * 64 + s * 32) * ldb,
          buf * BUFSZ + ASZ + half * 8192 + s * 4096 + ldsw);
  };

  f32x4 acc[4][4];
#pragma unroll
  for (int m = 0; m < 4; ++m)
#pragma unroll
    for (int n = 0; n < 4; ++n) acc[m][n] = (f32x4){0.f, 0.f, 0.f, 0.f};
  f32x4 rs[4];
#pragma unroll
  for (int m = 0; m < 4; ++m) rs[m] = (f32x4){0.f, 0.f, 0.f, 0.f};
  bf16x8 vones;
#pragma unroll
  for (int i = 0; i < 8; ++i) vones[i] = (bf16_t)1.0f;

  // ds_read fragment loaders (swizzled, conflict-free)
  auto ldA = [&](bf16x8 (&a)[2][2], int cur, int mq) {
#pragma unroll
    for (int i = 0; i < 2; ++i) {
      const int row = wm * 64 + (mq * 2 + i) * 16 + l15;
#pragma unroll
      for (int kk = 0; kk < 2; ++kk) {
        const int byt = cur * BUFSZ + row * 128 + ((kk * 64 + lq * 16) ^ ((row & 7) << 4));
        a[i][kk] = *(const bf16x8*)(smem + byt);
      }
    }
  };
  auto ldB = [&](bf16x8 (&b)[2][2], int cur, int nq) {
#pragma unroll
    for (int n2 = 0; n2 < 2; ++n2) {
      const int row = wn * 64 + (nq * 2 + n2) * 16 + l15;
#pragma unroll
      for (int kk = 0; kk < 2; ++kk) {
        const int byt = cur * BUFSZ + ASZ + row * 128 + ((kk * 64 + lq * 16) ^ ((row & 7) << 4));
        b[n2][kk] = *(const bf16x8*)(smem + byt);
      }
    }
  };
  auto mmaq = [&](bf16x8 (&a)[2][2], bf16x8 (&b)[2][2], int mq, int nq) {
    __builtin_amdgcn_s_setprio(1);
#pragma unroll
    for (int kk = 0; kk < 2; ++kk)
#pragma unroll
      for (int i = 0; i < 2; ++i)
#pragma unroll
        for (int n2 = 0; n2 < 2; ++n2)
          acc[mq * 2 + i][nq * 2 + n2] = __builtin_amdgcn_mfma_f32_16x16x32_bf16(
              a[i][kk], b[n2][kk], acc[mq * 2 + i][nq * 2 + n2], 0, 0, 0);
    __builtin_amdgcn_s_setprio(0);
  };
  auto mmars = [&](bf16x8 (&a)[2][2], int mq) {
#pragma unroll
    for (int kk = 0; kk < 2; ++kk)
#pragma unroll
      for (int i = 0; i < 2; ++i)
        rs[mq * 2 + i] = __builtin_amdgcn_mfma_f32_16x16x32_bf16(
            a[i][kk], vones, rs[mq * 2 + i], 0, 0, 0);
  };

  // ---------------- prologue: t0 full (8) + t1 {Bh0 (2), A (4)}; VMC6 -----------
  stB(0, 0, 0); stB(0, 0, 1); stA(0, 0);
  stB(1, 1, 0); stA(1, 1);
  VMC6();   // 14 outstanding -> retire tile0's 8, keep t1's 6
  BARR();

  bf16x8 a0[2][2], a1[2][2], b0[2][2], b1[2][2];
  // lean tile lambda -- round-10 size (inlines; acc stays in VGPRs)
  auto tile = [&](int t, int cur) {
    ldA(a0, cur, 0); ldB(b0, cur, 0);
    stB(t + 1, cur ^ 1, 1);
    BARR(); LGKM0();
    mmaq(a0, b0, 0, 0);
    BARR();
    ldB(b1, cur, 1);
    BARR(); LGKM0();
    mmaq(a0, b1, 0, 1);
    if constexpr (RS) mmars(a0, 0);
    BARR();
    ldA(a1, cur, 1);
    stB(t + 2, cur, 0);
    BARR(); LGKM0();
    mmaq(a1, b1, 1, 1);
    BARR();
    stA(t + 2, cur);
    BARR();
    mmaq(a1, b0, 1, 0);
    if constexpr (RS) mmars(a1, 1);
    VMC6();   // retire tile t+1's 8 loads; keep tile t+2's 6 in flight
    BARR();
  };

#pragma unroll
  for (int rep = 0; rep < REPS; ++rep) {
    const int tb = rep << NTL;
    for (int tt = 0; tt < NT; tt += 2) {
      tile(tb + tt, 0);
      tile(tb + tt + 1, 1);
    }

    // ---------- per-rep epilogue: STRAIGHT INLINE CODE (no call) --------------
    {
      int zz2, bm2, bn2;
      const float* biasp;
      void* Cvp;
      bool tr = false;
      if constexpr (QKV3) {
        zz2 = 0; bm2 = bmr0; bn2 = bnr0;
        biasp = rep == 0 ? bias : (rep == 1 ? bias1 : bias2);
        Cvp   = rep == 0 ? Cv   : (rep == 1 ? Cv1   : Cv2);
        tr = (rep == 2);
      } else {
        zz2 = (REPS >= 2 && rep) ? zzr1 : zzr0;
        bm2 = (REPS >= 2 && rep) ? bmr1 : bmr0;
        bn2 = (REPS >= 2 && rep) ? bnr1 : bnr0;
        biasp = bias; Cvp = Cv;
      }
      const int colb = bn2 * 128 + wn * 64 + l15;
      const int rowb = bm2 * 128 + wm * 64 + lq * 4;
#pragma unroll
      for (int m = 0; m < 4; ++m) {
        float inv[4];
        if constexpr (RS) {
#pragma unroll
          for (int j = 0; j < 4; ++j) inv[j] = 1.0f / rs[m][j];
        }
#pragma unroll
        for (int n = 0; n < 4; ++n) {
          const int colg = colb + n * 16;
          float bval = 0.0f;
          if constexpr (OUTMODE != 3) bval = biasp ? biasp[colg] : 0.0f;
          if (QKV3 && tr) {
            const int r0 = rowb + m * 16;
            bf16x4 pk;
#pragma unroll
            for (int j = 0; j < 4; ++j) pk[j] = (bf16_t)(acc[m][n][j] * scale + bval);
            const long bb = (long)(r0 >> 11);
            const int ss = r0 & (SEQ - 1);
            *(bf16x4*)((bf16_t*)Cvp + bb * ((long)E_DIM * SEQ) + (long)colg * SEQ + ss) = pk;
          } else {
#pragma unroll
            for (int j = 0; j < 4; ++j) {
              const int r = rowb + m * 16 + j;
              float v;
              if constexpr (OUTMODE == 3) v = __expf(acc[m][n][j] * scale);
              else v = acc[m][n][j] * scale + bval;
              if constexpr (RS) v *= inv[j];
              if (OUTMODE == 0 && residual) v += residual[(long)r * ldc + colg];
              const long idx = (long)zz2 * sC + (long)r * ldc + colg;
              if constexpr (OUTMODE == 0) ((float*)Cvp)[idx] = v;
              else ((bf16_t*)Cvp)[idx] = (bf16_t)v;
            }
          }
        }
      }
      if (rep + 1 < REPS) {
#pragma unroll
        for (int m = 0; m < 4; ++m) {
#pragma unroll
          for (int n = 0; n < 4; ++n) acc[m][n] = (f32x4){0.f, 0.f, 0.f, 0.f};
          rs[m] = (f32x4){0.f, 0.f, 0.f, 0.f};
        }
      }
    }
  }
  VMC0();
#undef GLL
}

// ---------------- layernorm in-place on rows of 1024 f32 ----------------
__global__ __launch_bounds__(256) void k_layernorm(float* __restrict__ out,
                                                   const float* __restrict__ gamma,
                                                   const float* __restrict__ beta) {
  const long row = blockIdx.x;
  float* rp = out + row * 1024;
  const int t = threadIdx.x;
  const float4 v = *(const float4*)(rp + t * 4);
  float s = v.x + v.y + v.z + v.w;
#pragma unroll
  for (int o = 32; o; o >>= 1) s += __shfl_xor(s, o);
  __shared__ float red1[4], red2[4];
  const int lane = t & 63, w = t >> 6;
  if (lane == 0) red1[w] = s;
  __syncthreads();
  const float mu = (red1[0] + red1[1] + red1[2] + red1[3]) * (1.0f / 1024.0f);
  const float d0 = v.x - mu, d1 = v.y - mu, d2 = v.z - mu, d3 = v.w - mu;
  float ss = d0 * d0 + d1 * d1 + d2 * d2 + d3 * d3;
#pragma unroll
  for (int o = 32; o; o >>= 1) ss += __shfl_xor(ss, o);
  if (lane == 0) red2[w] = ss;
  __syncthreads();
  const float var = (red2[0] + red2[1] + red2[2] + red2[3]) * (1.0f / 1024.0f);
  const float rsq = rsqrtf(var + 1e-6f);
  const float4 g = *(const float4*)(gamma + t * 4);
  const float4 b = *(const float4*)(beta + t * 4);
  float4 o;
  o.x = d0 * rsq * g.x + b.x;
  o.y = d1 * rsq * g.y + b.y;
  o.z = d2 * rsq * g.z + b.z;
  o.w = d3 * rsq * g.w + b.w;
  *(float4*)(rp + t * 4) = o;
}

extern "C" void kernel_launch(void* const* d_in, const int* in_sizes, int n_in,
                              void* d_out, int out_size, void* d_ws, size_t ws_size,
                              hipStream_t stream) {
  const float* query = (const float*)d_in[0];
  const float* key   = (const float*)d_in[1];
  const float* value = (const float*)d_in[2];
  const float* Wq = (const float*)d_in[3];
  const float* bq = (const float*)d_in[4];
  const float* Wk = (const float*)d_in[5];
  const float* bk = (const float*)d_in[6];
  const float* Wv = (const float*)d_in[7];
  const float* bv = (const float*)d_in[8];
  const float* Wo = (const float*)d_in[9];
  const float* bo = (const float*)d_in[10];
  const float* gamma = (const float*)d_in[11];
  const float* beta  = (const float*)d_in[12];
  float* out = (float*)d_out;

  char* ws = (char*)d_ws;
  const size_t XSZ = (size_t)NBATCH * SEQ * E_DIM * 2;  // 16 MiB
  const size_t WSZ = (size_t)E_DIM * E_DIM * 2;         // 2 MiB
  const size_t B2  = 3 * XSZ;                           // 48 MiB boundary

  bf16_t* Xq  = (bf16_t*)(ws + 0);
  bf16_t* Xk  = (bf16_t*)(ws + XSZ);
  bf16_t* Xv  = (bf16_t*)(ws + 2 * XSZ);
  bf16_t* SC  = (bf16_t*)(ws + 0);   // exp-scores overlay dead X buffers (33.5MB<48)
  bf16_t* Wqb = (bf16_t*)(ws + B2);
  bf16_t* Wkb = (bf16_t*)(ws + B2 + WSZ);
  bf16_t* Wvb = (bf16_t*)(ws + B2 + 2 * WSZ);
  bf16_t* Wob = (bf16_t*)(ws + B2 + 3 * WSZ);
  bf16_t* Qb  = (bf16_t*)(ws + B2 + 4 * WSZ);
  bf16_t* Kb  = (bf16_t*)(ws + B2 + 4 * WSZ + XSZ);
  bf16_t* Vt  = (bf16_t*)(ws + B2 + 4 * WSZ + 2 * XSZ);
  bf16_t* Ctx = (bf16_t*)(ws + B2 + 4 * WSZ + 3 * XSZ);

  const int NTOK = NBATCH * SEQ;  // 8192
  const int SMB = 65536;          // 2 x 32KB -> 2 wg/CU

  hipFuncSetAttribute((const void*)k_g13<1, false, true, 3, 4>, hipFuncAttributeMaxDynamicSharedMemorySize, SMB);
  hipFuncSetAttribute((const void*)k_g13<3, false, false, 2, 4>, hipFuncAttributeMaxDynamicSharedMemorySize, SMB);
  hipFuncSetAttribute((const void*)k_g13<1, true, false, 1, 5>, hipFuncAttributeMaxDynamicSharedMemorySize, SMB);
  hipFuncSetAttribute((const void*)k_g13<0, false, false, 1, 4>, hipFuncAttributeMaxDynamicSharedMemorySize, SMB);

  // 1) casts: 7168 blocks x 4096 elems (16/thread, 4 loads in flight)
  k_cast2<<<dim3(7168), 256, 0, stream>>>(query, key, value, Wq, Wk, Wv, Wo,
                                          Xq, Xk, Xv, Wqb, Wkb, Wvb, Wob);

  // 2) persistent merged Q/K/V projections: grid 512, REPS=3 slabs per wg
  k_g13<1, false, true, 3, 4><<<512, 256, SMB, stream>>>(
      Xq, E_DIM, 0, Wqb, E_DIM, 0, Qb, E_DIM, 0, 1.0f, bq, nullptr, 64, 8,
      Xk, Xv, Wkb, Wvb, bk, bv, Kb, Vt);

  // 3) P = exp(Q K^T / 32): grid 512, REPS=2 (16x16x4 = 1024 tiles)
  k_g13<3, false, false, 2, 4><<<512, 256, SMB, stream>>>(
      Qb, E_DIM, (long)SEQ * E_DIM, Kb, E_DIM, (long)SEQ * E_DIM,
      SC, SEQ, (long)SEQ * SEQ, 0.03125f, nullptr, nullptr, 16, 16,
      nullptr, nullptr, nullptr, nullptr, nullptr, nullptr, nullptr, nullptr);

  // 4) ctx = (P @ V) / rowsum: grid 512, REPS=1, NT=32
  k_g13<1, true, false, 1, 5><<<512, 256, SMB, stream>>>(
      SC, SEQ, (long)SEQ * SEQ, Vt, SEQ, (long)E_DIM * SEQ,
      Ctx, E_DIM, (long)SEQ * E_DIM, 1.0f, nullptr, nullptr, 16, 8,
      nullptr, nullptr, nullptr, nullptr, nullptr, nullptr, nullptr, nullptr);

  // 5) out = ctx Wo^T + bo + residual(query): grid 512, REPS=1
  k_g13<0, false, false, 1, 4><<<512, 256, SMB, stream>>>(
      Ctx, E_DIM, 0, Wob, E_DIM, 0, out, E_DIM, 0, 1.0f, bo, query, 64, 8,
      nullptr, nullptr, nullptr, nullptr, nullptr, nullptr, nullptr, nullptr);

  // 6) layernorm in-place
  k_layernorm<<<dim3(NTOK), 256, 0, stream>>>(out, gamma, beta);
}